// Round 12
// baseline (885.849 us; speedup 1.0000x reference)
//
#include <hip/hip_runtime.h>

#define NPTS 12288
#define DIMS 8
#define EPS2 0.25f
#define MINS 5
#define NW   (NPTS / 32)       // 384 words per adjacency row
#define RMAX 512               // max contracted labels (R~120 measured OK)
#define W    (RMAX / 32)       // 16 words per contracted-bitmap row
#define BIGL 0x3fffffff

// mega-kernel geometry: 256 blocks x 512 thr; LDS ~58KB -> 2 blocks/CU capacity
// => all 256 blocks resident => hand-rolled grid barrier is deadlock-free.
#define MB   256
#define MT   512
#define MW   (MB * MT / 64)    // 2048 waves

// k_adj geometry (R10-verified): 256 thr x 2 rows; j-chunk 256 = 8 words = 32B
#define ATHR 256
#define ATI  512
#define ANIB (NPTS / ATI)      // 24
#define ANJB 48
#define AJC  (NPTS / ANJB)     // 256
#define AWCH (AJC / 32)        // 8

typedef float v2f __attribute__((ext_vector_type(2)));

__device__ __forceinline__ float dot8(const v2f* xi, const float4& a, const float4& b) {
  v2f y0 = {a.x, a.y}, y1 = {a.z, a.w}, y2 = {b.x, b.y}, y3 = {b.z, b.w};
  v2f d = xi[0] * y0;
  d = __builtin_elementwise_fma(xi[1], y1, d);
  d = __builtin_elementwise_fma(xi[2], y2, d);
  d = __builtin_elementwise_fma(xi[3], y3, d);
  return d.x + d.y;
}

// ---------------- k_adj: the ONLY N^2 distance pass (no density atomics) ----
__global__ __launch_bounds__(ATHR) void k_adj(const float* __restrict__ X,
                                              unsigned int* __restrict__ adj) {
  __shared__ float4 xs[AJC][2];
  __shared__ float sqs[AJC];
  int t = threadIdx.x;
  int j0 = blockIdx.y * AJC;
  {
    int j = j0 + t;
    float4 a = ((const float4*)X)[j * 2];
    float4 b = ((const float4*)X)[j * 2 + 1];
    xs[t][0] = a; xs[t][1] = b;
    float sv = 0.f;
    sv = fmaf(a.x, a.x, sv); sv = fmaf(a.y, a.y, sv); sv = fmaf(a.z, a.z, sv); sv = fmaf(a.w, a.w, sv);
    sv = fmaf(b.x, b.x, sv); sv = fmaf(b.y, b.y, sv); sv = fmaf(b.z, b.z, sv); sv = fmaf(b.w, b.w, sv);
    sqs[t] = sv;
  }
  int i0 = blockIdx.x * ATI + t, i1 = i0 + ATHR;
  v2f xi0[4], xi1[4];
  {
    float4 a0 = ((const float4*)X)[i0 * 2], b0v = ((const float4*)X)[i0 * 2 + 1];
    float4 a1 = ((const float4*)X)[i1 * 2], b1v = ((const float4*)X)[i1 * 2 + 1];
    xi0[0] = (v2f){a0.x, a0.y}; xi0[1] = (v2f){a0.z, a0.w};
    xi0[2] = (v2f){b0v.x, b0v.y}; xi0[3] = (v2f){b0v.z, b0v.w};
    xi1[0] = (v2f){a1.x, a1.y}; xi1[1] = (v2f){a1.z, a1.w};
    xi1[2] = (v2f){b1v.x, b1v.y}; xi1[3] = (v2f){b1v.z, b1v.w};
  }
  float sq0 = 0.f, sq1 = 0.f;
#pragma unroll
  for (int q = 0; q < 4; q++) {
    v2f p0 = xi0[q] * xi0[q], p1 = xi1[q] * xi1[q];
    sq0 += p0.x + p0.y; sq1 += p1.x + p1.y;
  }
  __syncthreads();
  unsigned int acc0[AWCH], acc1[AWCH];
#pragma unroll
  for (int w = 0; w < AWCH; w++) {
    unsigned int b0 = 0u, b1 = 0u;
#pragma unroll 4
    for (int bit = 0; bit < 32; bit++) {
      int jj = (w << 5) + bit;
      float4 xa = xs[jj][0], xb = xs[jj][1];
      float sj = sqs[jj];
      unsigned int m = 1u << bit;
      float d20 = (sq0 + sj) - 2.0f * dot8(xi0, xa, xb);
      float d21 = (sq1 + sj) - 2.0f * dot8(xi1, xa, xb);
      if (d20 <= EPS2) b0 |= m;
      if (d21 <= EPS2) b1 |= m;
    }
    acc0[w] = b0; acc1[w] = b1;
  }
  uint4* dst0 = (uint4*)(adj + (size_t)i0 * NW + blockIdx.y * AWCH);
  uint4* dst1 = (uint4*)(adj + (size_t)i1 * NW + blockIdx.y * AWCH);
  dst0[0] = make_uint4(acc0[0], acc0[1], acc0[2], acc0[3]);
  dst0[1] = make_uint4(acc0[4], acc0[5], acc0[6], acc0[7]);
  dst1[0] = make_uint4(acc1[0], acc1[1], acc1[2], acc1[3]);
  dst1[1] = make_uint4(acc1[4], acc1[5], acc1[6], acc1[7]);
}

// ---------------- grid barrier (all MB blocks resident; acq invalidates L1) --
__device__ __forceinline__ void gridbar(int* cnt, int* gen, int t) {
  __syncthreads();
  __threadfence();
  if (t == 0) {
    int g = __hip_atomic_load(gen, __ATOMIC_RELAXED, __HIP_MEMORY_SCOPE_AGENT);
    int v = __hip_atomic_fetch_add(cnt, 1, __ATOMIC_ACQ_REL, __HIP_MEMORY_SCOPE_AGENT);
    if (v == MB - 1) {
      __hip_atomic_store(cnt, 0, __ATOMIC_RELAXED, __HIP_MEMORY_SCOPE_AGENT);
      __hip_atomic_fetch_add(gen, 1, __ATOMIC_ACQ_REL, __HIP_MEMORY_SCOPE_AGENT);
    } else {
      while (__hip_atomic_load(gen, __ATOMIC_ACQUIRE, __HIP_MEMORY_SCOPE_AGENT) == g)
        __builtin_amdgcn_s_sleep(8);
    }
  }
  __syncthreads();
}

// ---------------- mega kernel: everything after k_adj ------------------------
__global__ __launch_bounds__(MT) void k_mega(const unsigned int* __restrict__ adj,
                                             int* __restrict__ density,
                                             int* __restrict__ hook,
                                             int* __restrict__ labL,
                                             int* __restrict__ labArr,
                                             int* __restrict__ blist,
                                             unsigned int* __restrict__ bm,
                                             int* __restrict__ clabG,
                                             int* __restrict__ Rptr,
                                             int* __restrict__ cnt,
                                             int* __restrict__ gen,
                                             int* __restrict__ bcount,
                                             float* __restrict__ out) {
  __shared__ unsigned long long cb64S[NW / 2];  // 1.5 KB core bitmap (persists)
  __shared__ unsigned int big[RMAX * W + NPTS / 2];  // 32KB + 24KB phase union
  __shared__ int wsum[MT / 64];
  __shared__ int chg, cmp;
  unsigned int* cbS = (unsigned int*)cb64S;
  int t = threadIdx.x;
  int lane = t & 63, wv = t >> 6;
  int gw = blockIdx.x * (MT / 64) + wv;          // global wave id 0..2047

  // ---- phase A: density = popcount(row); block 0 zeroes bm ----
  if (blockIdx.x == 0)
    for (int q = t; q < RMAX * W; q += MT) bm[q] = 0u;
  for (int i = gw; i < NPTS; i += MW) {
    const uint4* row = (const uint4*)(adj + (size_t)i * NW);
    uint4 v = row[lane];
    int s = __popc(v.x) + __popc(v.y) + __popc(v.z) + __popc(v.w);
    if (lane < NW / 4 - 64) {
      uint4 v2 = row[64 + lane];
      s += __popc(v2.x) + __popc(v2.y) + __popc(v2.z) + __popc(v2.w);
    }
#pragma unroll
    for (int off = 32; off >= 1; off >>= 1) s += __shfl_xor(s, off, 64);
    if (lane == 0) density[i] = s;
  }
  gridbar(cnt, gen, t);

  // ---- phase B: build core bitmap in LDS (ballot) + hook (wave-per-row) ----
  for (int base = 0; base < NPTS; base += MT) {
    int i = base + t;
    unsigned long long m = __ballot(density[i] >= MINS);
    if ((t & 63) == 0) cb64S[i >> 6] = m;
  }
  __syncthreads();
  for (int i = gw; i < NPTS; i += MW) {
    const unsigned int* row = adj + (size_t)i * NW;
    int wi = i >> 5;
    int m = i;
    for (int w = lane; w <= wi; w += 64) {
      unsigned int x = row[w] & cbS[w];
      if (w == wi) x &= (1u << (i & 31)) - 1u;   // bits strictly below i
      if (x) m = min(m, (w << 5) + __ffs(x) - 1);
    }
#pragma unroll
    for (int off = 32; off >= 1; off >>= 1) m = min(m, __shfl_xor(m, off, 64));
    if (lane == 0) hook[i] = m;
  }
  gridbar(cnt, gen, t);

  // ---- phase C (block 0): root-rank scan + forest chase -> labL ----
  if (blockIdx.x == 0) {
    unsigned short* ridS = (unsigned short*)big;   // 24 KB
    const int SEG = NPTS / MT;                     // 24
    int base = t * SEG;
    int flags = 0, s = 0;
    for (int k = 0; k < SEG; k++) {
      int i = base + k;
      int f = (density[i] >= MINS && hook[i] == i) ? 1 : 0;
      flags |= f << k;
      s += f;
    }
    int segsum = s;
#pragma unroll
    for (int off = 1; off < 64; off <<= 1) {
      int n = __shfl_up(s, off, 64);
      if (lane >= off) s += n;
    }
    if (lane == 63) wsum[wv] = s;
    __syncthreads();
    int woff = 0;
    for (int w = 0; w < wv; w++) woff += wsum[w];
    int run = woff + s - segsum;
    for (int k = 0; k < SEG; k++) {
      ridS[base + k] = (unsigned short)run;
      run += (flags >> k) & 1;
    }
    if (t == MT - 1) *Rptr = run;
    __syncthreads();
    for (int k = 0; k < SEG; k++) {
      int i = base + k;
      int lab = -1;
      if (density[i] >= MINS) {
        int v = i, h = hook[v];                    // strictly decreasing chain
        while (h != v) { v = h; h = hook[v]; }
        lab = min((int)ridS[v], RMAX - 1);
      }
      labL[i] = lab;
    }
  }
  gridbar(cnt, gen, t);

  // ---- phase D: fillbm (crossing edges, j>i, LDS bitmap + batched merge) ----
  {
    unsigned int* bmL = big;                                   // 32 KB
    unsigned short* labS = (unsigned short*)(big + RMAX * W);  // 24 KB
    for (int q = t; q < RMAX * W; q += MT) bmL[q] = 0u;
    for (int q = t; q < NPTS; q += MT) labS[q] = (unsigned short)(labL[q] + 1);
    __syncthreads();
    for (int i = gw; i < NPTS; i += MW) {
      int a0 = (int)labS[i] - 1;
      if (a0 < 0) continue;                        // wave-uniform
      const unsigned int* row = adj + (size_t)i * NW;
      int wi = i >> 5;
      for (int w = wi + lane; w < NW; w += 64) {
        unsigned int x = row[w] & cbS[w];
        if (w == wi) x &= (0xFFFFFFFEu << (i & 31));
        while (x) {
          int b = __ffs(x) - 1; x &= x - 1;
          int lj = (int)labS[(w << 5) + b] - 1;
          if (lj != a0) {
            atomicOr(&bmL[a0 * W + (lj >> 5)], 1u << (lj & 31));
            atomicOr(&bmL[lj * W + (a0 >> 5)], 1u << (a0 & 31));
          }
        }
      }
    }
    __syncthreads();
    for (int q = t; q < RMAX * W; q += MT) {
      unsigned int v = bmL[q];
      if (v) atomicOr(&bm[q], v);
    }
  }
  gridbar(cnt, gen, t);

  // ---- phase E (block 0): CC of contracted graph + compact cluster ids ----
  if (blockIdx.x == 0) {
    int* lbl = (int*)big;
    int* mn = lbl + RMAX;
    int a = t;   // MT == RMAX
    int R = *Rptr; if (R > RMAX) R = RMAX;
    lbl[a] = a;
    __syncthreads();
    while (true) {
      int m = lbl[a];
      if (a < R) {
        const unsigned int* row = bm + a * W;
#pragma unroll
        for (int w = 0; w < W; w++) {
          unsigned int bits = row[w];
          while (bits) {
            int b = __ffs(bits) - 1;
            bits &= bits - 1;
            m = min(m, lbl[(w << 5) + b]);
          }
        }
      }
      mn[a] = m;
      if (a == 0) chg = 0;
      __syncthreads();
      int l = lbl[a];
      if (m < l) { atomicMin(&lbl[l], m); atomicMin(&lbl[a], m); chg = 1; }
      __syncthreads();
      while (true) {
        if (a == 0) cmp = 0;
        __syncthreads();
        int nl = lbl[lbl[a]];
        __syncthreads();
        if (nl < lbl[a]) { lbl[a] = nl; cmp = 1; }
        __syncthreads();
        if (!cmp) break;
      }
      if (!chg) break;
      __syncthreads();
    }
    int flag = (a < R && lbl[a] == a) ? 1 : 0;
    mn[a] = flag;
    __syncthreads();
    for (int off = 1; off < RMAX; off <<= 1) {
      int v = mn[a];
      int add = (a >= off) ? mn[a - off] : 0;
      __syncthreads();
      mn[a] = v + add;
      __syncthreads();
    }
    clabG[a] = mn[lbl[a]] - 1;
  }
  gridbar(cnt, gen, t);

  // ---- phase F: per-point labels + border list (parallel, 24 blocks work) --
  {
    int gid = blockIdx.x * MT + t;
    if (gid < NPTS) {
      int l = labL[gid];
      if (l >= 0) {
        int lab = clabG[l];
        labArr[gid] = lab;
        out[gid] = (float)lab;
      } else {
        labArr[gid] = BIGL;
        out[gid] = -1.0f;
        int pos = atomicAdd(bcount, 1);
        blist[pos] = gid;
      }
    }
  }
  gridbar(cnt, gen, t);

  // ---- phase G: border points (block-per-point, bitmap scan) ----
  {
    int count = *bcount;
    for (int k = blockIdx.x; k < count; k += MB) {
      int p = blist[k];
      const unsigned int* row = adj + (size_t)p * NW;
      int m = BIGL;
      if (t < NW) {
        unsigned int x = row[t] & cbS[t];
        while (x) {
          int b = __ffs(x) - 1; x &= x - 1;
          m = min(m, labArr[(t << 5) + b]);
        }
      }
#pragma unroll
      for (int off = 32; off >= 1; off >>= 1) m = min(m, __shfl_xor(m, off, 64));
      if (lane == 0) wsum[wv] = m;
      __syncthreads();
      if (t == 0) {
        int mm = wsum[0];
        for (int w = 1; w < MT / 64; w++) mm = min(mm, wsum[w]);
        out[p] = (mm < BIGL) ? (float)mm : -1.0f;
      }
      __syncthreads();
    }
  }
}

// ---------------- launch ----------------

extern "C" void kernel_launch(void* const* d_in, const int* in_sizes, int n_in,
                              void* d_out, int out_size, void* d_ws, size_t ws_size,
                              hipStream_t stream) {
  const float* X = (const float*)d_in[0];
  float* out = (float*)d_out;

  char* ws = (char*)d_ws;
  unsigned int* adj = (unsigned int*)ws;                     // 18,874,368 B
  size_t off = (size_t)NPTS * NW * 4;
  int* density = (int*)(ws + off);           off += 4 * NPTS;
  int* hook    = (int*)(ws + off);           off += 4 * NPTS;
  int* labL    = (int*)(ws + off);           off += 4 * NPTS;
  int* labArr  = (int*)(ws + off);           off += 4 * NPTS;
  int* blist   = (int*)(ws + off);           off += 4 * NPTS;
  unsigned int* bm = (unsigned int*)(ws + off); off += 4 * RMAX * W;
  int* clabG   = (int*)(ws + off);           off += 4 * RMAX;
  int* Rptr    = (int*)(ws + off);           off += 4;
  int* ctrl    = (int*)(ws + off);           // cnt, gen, bcount
  int* cnt = ctrl, *gen = ctrl + 1, *bcount = ctrl + 2;

  hipMemsetAsync(ctrl, 0, 12, stream);

  dim3 gridA(ANIB, ANJB);   // 24 x 48 = 1152 blocks x 4 waves

  k_adj<<<gridA, ATHR, 0, stream>>>(X, adj);
  k_mega<<<MB, MT, 0, stream>>>(adj, density, hook, labL, labArr, blist,
                                bm, clabG, Rptr, cnt, gen, bcount, out);
}

// Round 13
// 275.805 us; speedup vs baseline: 3.2119x; 3.2119x over previous
//
#include <hip/hip_runtime.h>

#define NPTS 12288
#define DIMS 8
#define EPS2 0.25f
#define MINS 5
#define NIB1 (NPTS / 256)      // 48
#define NW   (NPTS / 32)       // 384 words per adjacency row
#define RMAX 512               // max contracted labels (R~120 measured OK)
#define W    (RMAX / 32)       // 16 words per contracted-bitmap row
#define BIGL 0x3fffffff
#define FT   128               // threads for border kernel
#define FB   256               // threads for fillbm
#define FBGRID 256             // blocks for fillbm -> 1024 waves

// k_adj (ballot form): block covers 512 i x 256 j; each lane holds 2 i's;
// per j, two wave-ballots emit 2x64 adjacency bits of (transposed==same) row j.
#define ATHR 256
#define AI   512
#define ANIB (NPTS / AI)       // 24
#define AJC  256
#define ANJB (NPTS / AJC)      // 48

typedef float v2f __attribute__((ext_vector_type(2)));

// packed-fp32 dot (R10-verified expression, commutative-exact)
__device__ __forceinline__ float dot8(const v2f* xi, const float4& a, const float4& b) {
  v2f y0 = {a.x, a.y}, y1 = {a.z, a.w}, y2 = {b.x, b.y}, y3 = {b.z, b.w};
  v2f d = xi[0] * y0;
  d = __builtin_elementwise_fma(xi[1], y1, d);
  d = __builtin_elementwise_fma(xi[2], y2, d);
  d = __builtin_elementwise_fma(xi[3], y3, d);
  return d.x + d.y;
}

// scalar-fmaf sq chain -- SAME expression for register side and LDS side
__device__ __forceinline__ float sq8(const float4& a, const float4& b) {
  float s = 0.f;
  s = fmaf(a.x, a.x, s); s = fmaf(a.y, a.y, s); s = fmaf(a.z, a.z, s); s = fmaf(a.w, a.w, s);
  s = fmaf(b.x, b.x, s); s = fmaf(b.y, b.y, s); s = fmaf(b.z, b.z, s); s = fmaf(b.w, b.w, s);
  return s;
}

// ---------------- kernels ----------------

// the ONLY N^2 distance pass. Wave-uniform j vs 64 lane-i's; __ballot packs
// 64 results into one word-pair of row j (matrix is exactly symmetric).
__global__ __launch_bounds__(ATHR) void k_adj(const float* __restrict__ X,
                                              unsigned int* __restrict__ adj) {
  __shared__ float4 xs[AJC][2];
  __shared__ float sqs[AJC];
  int t = threadIdx.x;
  int lane = t & 63, wv = t >> 6;
  int j0 = blockIdx.y * AJC;
  {
    int j = j0 + t;
    float4 a = ((const float4*)X)[j * 2];
    float4 b = ((const float4*)X)[j * 2 + 1];
    xs[t][0] = a; xs[t][1] = b;
    sqs[t] = sq8(a, b);
  }
  int ib = blockIdx.x * AI;
  int i0 = ib + wv * 64 + lane, i1 = i0 + 256;
  v2f xi0[4], xi1[4];
  float sq0, sq1;
  {
    float4 a0 = ((const float4*)X)[i0 * 2], b0 = ((const float4*)X)[i0 * 2 + 1];
    float4 a1 = ((const float4*)X)[i1 * 2], b1 = ((const float4*)X)[i1 * 2 + 1];
    xi0[0] = (v2f){a0.x, a0.y}; xi0[1] = (v2f){a0.z, a0.w};
    xi0[2] = (v2f){b0.x, b0.y}; xi0[3] = (v2f){b0.z, b0.w};
    xi1[0] = (v2f){a1.x, a1.y}; xi1[1] = (v2f){a1.z, a1.w};
    xi1[2] = (v2f){b1.x, b1.y}; xi1[3] = (v2f){b1.z, b1.w};
    sq0 = sq8(a0, b0);         // identical chain as sqs -> adj exactly symmetric
    sq1 = sq8(a1, b1);
  }
  __syncthreads();
#pragma unroll 4
  for (int jj = 0; jj < AJC; jj++) {
    float4 xa = xs[jj][0], xb = xs[jj][1];
    float sj = sqs[jj];
    float d20 = (sq0 + sj) - 2.0f * dot8(xi0, xa, xb);
    float d21 = (sq1 + sj) - 2.0f * dot8(xi1, xa, xb);
    unsigned long long b0 = __ballot(d20 <= EPS2);
    unsigned long long b1 = __ballot(d21 <= EPS2);
    unsigned long long* rowq =
        (unsigned long long*)(adj + (size_t)(j0 + jj) * NW) + (ib >> 6);
    if (lane == 0) {
      rowq[wv] = b0;           // i's [ib+64wv, ib+64wv+63]
      rowq[wv + 4] = b1;       // i's +256
    }
  }
}

// density = popcount(row), wave-per-row (384 waves)
__global__ __launch_bounds__(256) void k_dens(const unsigned int* __restrict__ adj,
                                              int* __restrict__ density) {
  int t = threadIdx.x, lane = t & 63, wv = t >> 6;
  int gw = blockIdx.x * 4 + wv;
  for (int i = gw; i < NPTS; i += 384) {
    const uint4* row = (const uint4*)(adj + (size_t)i * NW);
    uint4 v = row[lane];
    int s = __popc(v.x) + __popc(v.y) + __popc(v.z) + __popc(v.w);
    if (lane < 32) {
      uint4 v2 = row[64 + lane];
      s += __popc(v2.x) + __popc(v2.y) + __popc(v2.z) + __popc(v2.w);
    }
#pragma unroll
    for (int off = 32; off >= 1; off >>= 1) s += __shfl_xor(s, off, 64);
    if (lane == 0) density[i] = s;
  }
}

// corebm via ballot; block 0 zeroes the contracted bitmap  (R10 verbatim)
__global__ __launch_bounds__(256) void k_core(const int* __restrict__ density,
                                              unsigned long long* __restrict__ corebm,
                                              unsigned int* __restrict__ bm) {
  int t = threadIdx.x;
  if (blockIdx.x == 0) {
#pragma unroll
    for (int q = 0; q < RMAX * W / 256; q++) bm[t + q * 256] = 0u;
  }
  int i = blockIdx.x * 256 + t;
  unsigned long long m = __ballot(density[i] >= MINS);
  if ((t & 63) == 0) corebm[i >> 6] = m;
}

// hook[i] = min(i, first core neighbor j<i)  (R10 verbatim)
__global__ __launch_bounds__(256) void k_hookbm(const unsigned int* __restrict__ adj,
                                                const unsigned int* __restrict__ cb32,
                                                int* __restrict__ hook) {
  __shared__ unsigned int cb[NW];
  int t = threadIdx.x;
  for (int w = t; w < NW; w += 256) cb[w] = cb32[w];
  __syncthreads();
  int i = blockIdx.x * 256 + t;
  const unsigned int* row = adj + (size_t)i * NW;
  int wi = i >> 5;
  int m = i;
  for (int w = 0; w <= wi; w++) {
    unsigned int x = row[w] & cb[w];
    if (w == wi) x &= (1u << (i & 31)) - 1;   // bits strictly below i
    if (x) { m = (w << 5) + __ffs(x) - 1; break; }  // first hit = min
  }
  hook[i] = m;
}

// root ranks in LDS + hook-chase (fused compress) + labL  (R10 verbatim)
__global__ __launch_bounds__(1024) void k_rid(const int* __restrict__ density,
                                              const int* __restrict__ hook,
                                              int* __restrict__ Rptr,
                                              int* __restrict__ labL,
                                              int* __restrict__ bcount) {
  __shared__ unsigned short ridS[NPTS];
  __shared__ int wsum[16];
  int t = threadIdx.x;
  int lane = t & 63, wid = t >> 6;
  const int SEG = NPTS / 1024;  // 12
  int base = t * SEG;
  int flags = 0;
  int s = 0;
#pragma unroll
  for (int k = 0; k < SEG; k++) {
    int i = base + k;
    int f = (density[i] >= MINS && hook[i] == i) ? 1 : 0;
    flags |= f << k;
    s += f;
  }
  int segsum = s;
#pragma unroll
  for (int off = 1; off < 64; off <<= 1) {
    int n = __shfl_up(s, off, 64);
    if (lane >= off) s += n;
  }
  if (lane == 63) wsum[wid] = s;
  __syncthreads();
  int woff = 0;
  for (int w = 0; w < wid; w++) woff += wsum[w];
  int run = woff + s - segsum;
#pragma unroll
  for (int k = 0; k < SEG; k++) {
    ridS[base + k] = (unsigned short)run;
    run += (flags >> k) & 1;
  }
  if (t == 1023) *Rptr = run;
  if (t == 0) *bcount = 0;
  __syncthreads();
  for (int k = 0; k < SEG; k++) {
    int i = base + k;
    int lab = -1;
    if (density[i] >= MINS) {
      int v = i, h = hook[v];
      while (h != v) { v = h; h = hook[v]; }
      lab = min((int)ridS[v], RMAX - 1);
    }
    labL[i] = lab;
  }
}

// crossing-label edges -> contracted adjacency  (R10 verbatim)
__global__ __launch_bounds__(FB) void k_fillbm(const unsigned int* __restrict__ adj,
                                               const unsigned int* __restrict__ cb32,
                                               const int* __restrict__ labL,
                                               unsigned int* __restrict__ bm) {
  __shared__ unsigned int bmL[RMAX * W];
  __shared__ unsigned short labS[NPTS];
  __shared__ unsigned int cb[NW];
  int t = threadIdx.x;
  for (int q = t; q < RMAX * W; q += FB) bmL[q] = 0u;
  for (int q = t; q < NPTS; q += FB) labS[q] = (unsigned short)(labL[q] + 1);
  for (int w = t; w < NW; w += FB) cb[w] = cb32[w];
  __syncthreads();
  int lane = t & 63, wv = t >> 6;
  int gw = blockIdx.x * 4 + wv;
  for (int i = gw; i < NPTS; i += 4 * FBGRID) {
    int a0 = (int)labS[i] - 1;
    if (a0 < 0) continue;
    const unsigned int* row = adj + (size_t)i * NW;
    int wi = i >> 5;
    for (int w = wi + lane; w < NW; w += 64) {
      unsigned int x = row[w] & cb[w];
      if (w == wi) x &= (0xFFFFFFFEu << (i & 31));
      while (x) {
        int b = __ffs(x) - 1; x &= x - 1;
        int lj = (int)labS[(w << 5) + b] - 1;
        if (lj != a0) {
          atomicOr(&bmL[a0 * W + (lj >> 5)], 1u << (lj & 31));
          atomicOr(&bmL[lj * W + (a0 >> 5)], 1u << (a0 & 31));
        }
      }
    }
  }
  __syncthreads();
  for (int q = t; q < RMAX * W; q += FB) {
    unsigned int v = bmL[q];
    if (v) atomicOr(&bm[q], v);
  }
}

// CC of contracted graph + compact cluster ids  (R10 verbatim)
__global__ __launch_bounds__(RMAX) void k_cc(const unsigned int* __restrict__ bm,
                                             const int* __restrict__ Rptr,
                                             int* __restrict__ clab) {
  __shared__ int lbl[RMAX];
  __shared__ int mn[RMAX];
  __shared__ int chg, cmp;
  int a = threadIdx.x;
  int R = *Rptr; if (R > RMAX) R = RMAX;
  lbl[a] = a;
  __syncthreads();
  while (true) {
    int m = lbl[a];
    if (a < R) {
      const unsigned int* row = bm + a * W;
#pragma unroll
      for (int w = 0; w < W; w++) {
        unsigned int bits = row[w];
        while (bits) {
          int b = __ffs(bits) - 1;
          bits &= bits - 1;
          m = min(m, lbl[(w << 5) + b]);
        }
      }
    }
    mn[a] = m;
    if (a == 0) chg = 0;
    __syncthreads();
    int l = lbl[a];
    if (m < l) { atomicMin(&lbl[l], m); atomicMin(&lbl[a], m); chg = 1; }
    __syncthreads();
    while (true) {
      if (a == 0) cmp = 0;
      __syncthreads();
      int nl = lbl[lbl[a]];
      __syncthreads();
      if (nl < lbl[a]) { lbl[a] = nl; cmp = 1; }
      __syncthreads();
      if (!cmp) break;
    }
    if (!chg) break;
    __syncthreads();
  }
  int flag = (a < R && lbl[a] == a) ? 1 : 0;
  mn[a] = flag;
  __syncthreads();
  for (int off = 1; off < RMAX; off <<= 1) {
    int v = mn[a];
    int add = (a >= off) ? mn[a - off] : 0;
    __syncthreads();
    mn[a] = v + add;
    __syncthreads();
  }
  clab[a] = mn[lbl[a]] - 1;
}

// per-point labels + border list  (R10 verbatim)
__global__ __launch_bounds__(256) void k_labels(const int* __restrict__ labL,
                                                const int* __restrict__ clab,
                                                int* __restrict__ labArr,
                                                int* __restrict__ blist,
                                                int* __restrict__ bcount,
                                                float* __restrict__ out) {
  int i = blockIdx.x * blockDim.x + threadIdx.x;
  if (i >= NPTS) return;
  int a = labL[i];
  if (a >= 0) {
    int lab = clab[a];
    labArr[i] = lab;
    out[i] = (float)lab;
  } else {
    labArr[i] = BIGL;
    out[i] = -1.0f;
    int pos = atomicAdd(bcount, 1);
    blist[pos] = i;
  }
}

// border points  (R10 verbatim)
__global__ __launch_bounds__(FT) void k_border(const unsigned int* __restrict__ adj,
                                               const unsigned int* __restrict__ cb32,
                                               const int* __restrict__ labArr,
                                               const int* __restrict__ blist,
                                               const int* __restrict__ bcount,
                                               float* __restrict__ out) {
  __shared__ unsigned int cb[NW];
  __shared__ int wm[FT / 64];
  int t = threadIdx.x;
  for (int w = t; w < NW; w += FT) cb[w] = cb32[w];
  __syncthreads();
  int count = *bcount;
  for (int k = blockIdx.x; k < count; k += gridDim.x) {
    int p = blist[k];
    const unsigned int* row = adj + (size_t)p * NW;
    int m = BIGL;
    for (int w = t; w < NW; w += FT) {
      unsigned int x = row[w] & cb[w];
      while (x) {
        int b = __ffs(x) - 1; x &= x - 1;
        m = min(m, labArr[(w << 5) + b]);
      }
    }
#pragma unroll
    for (int off = 32; off >= 1; off >>= 1) m = min(m, __shfl_xor(m, off, 64));
    if ((t & 63) == 0) wm[t >> 6] = m;
    __syncthreads();
    if (t == 0) {
      int mm = min(wm[0], wm[1]);
      out[p] = (mm < BIGL) ? (float)mm : -1.0f;
    }
    __syncthreads();
  }
}

// ---------------- launch ----------------

extern "C" void kernel_launch(void* const* d_in, const int* in_sizes, int n_in,
                              void* d_out, int out_size, void* d_ws, size_t ws_size,
                              hipStream_t stream) {
  const float* X = (const float*)d_in[0];
  float* out = (float*)d_out;

  char* ws = (char*)d_ws;
  unsigned int* adj = (unsigned int*)ws;                     // 18,874,368 B
  size_t off = (size_t)NPTS * NW * 4;
  int* density = (int*)(ws + off);           off += 4 * NPTS;
  int* hook    = (int*)(ws + off);           off += 4 * NPTS;
  int* labL    = (int*)(ws + off);           off += 4 * NPTS;
  int* labArr  = (int*)(ws + off);           off += 4 * NPTS;
  int* blist   = (int*)(ws + off);           off += 4 * NPTS;
  unsigned long long* corebm = (unsigned long long*)(ws + off); off += 2048;
  unsigned int* bm = (unsigned int*)(ws + off); off += 4 * RMAX * W;
  int* clab    = (int*)(ws + off);           off += 4 * RMAX;
  int* Rptr    = (int*)(ws + off);
  int* bcount  = Rptr + 1;

  dim3 gridA(ANIB, ANJB);   // 24 x 48 = 1152 blocks x 4 waves

  k_adj<<<gridA, ATHR, 0, stream>>>(X, adj);
  k_dens<<<96, 256, 0, stream>>>(adj, density);
  k_core<<<NIB1, 256, 0, stream>>>(density, corebm, bm);
  k_hookbm<<<NIB1, 256, 0, stream>>>(adj, (const unsigned int*)corebm, hook);
  k_rid<<<1, 1024, 0, stream>>>(density, hook, Rptr, labL, bcount);
  k_fillbm<<<FBGRID, FB, 0, stream>>>(adj, (const unsigned int*)corebm, labL, bm);
  k_cc<<<1, RMAX, 0, stream>>>(bm, Rptr, clab);
  k_labels<<<NIB1, 256, 0, stream>>>(labL, clab, labArr, blist, bcount, out);
  k_border<<<256, FT, 0, stream>>>(adj, (const unsigned int*)corebm, labArr, blist, bcount, out);
}

// Round 14
// 231.225 us; speedup vs baseline: 3.8311x; 1.1928x over previous
//
#include <hip/hip_runtime.h>

#define NPTS 12288
#define DIMS 8
#define EPS2 0.25f
#define MINS 5
#define NIB1 (NPTS / 256)      // 48
#define NW   (NPTS / 32)       // 384 words per adjacency row
#define RMAX 512               // max contracted labels (R~120 measured OK)
#define W    (RMAX / 32)       // 16 words per contracted-bitmap row
#define BIGL 0x3fffffff
#define FT   128               // threads for border kernel
#define FB   256               // threads for fillbm
#define FBGRID 256             // blocks for fillbm -> 1024 waves

// k_adj (staged-ballot): tile = 512 i x 128 j; 2 i's per lane; ballots staged
// in LDS, stored as full 64B lines; density fused. Grid 24x96 = 9 waves/SIMD.
#define ATHR 256
#define AI   512
#define ANIB (NPTS / AI)       // 24
#define AJC  128
#define ANJB (NPTS / AJC)      // 96

typedef float v2f __attribute__((ext_vector_type(2)));

// packed-fp32 dot (R10/R13-verified expression, commutative-exact)
__device__ __forceinline__ float dot8(const v2f* xi, const float4& a, const float4& b) {
  v2f y0 = {a.x, a.y}, y1 = {a.z, a.w}, y2 = {b.x, b.y}, y3 = {b.z, b.w};
  v2f d = xi[0] * y0;
  d = __builtin_elementwise_fma(xi[1], y1, d);
  d = __builtin_elementwise_fma(xi[2], y2, d);
  d = __builtin_elementwise_fma(xi[3], y3, d);
  return d.x + d.y;
}

// scalar-fmaf sq chain -- SAME expression register-side and LDS-side
__device__ __forceinline__ float sq8(const float4& a, const float4& b) {
  float s = 0.f;
  s = fmaf(a.x, a.x, s); s = fmaf(a.y, a.y, s); s = fmaf(a.z, a.z, s); s = fmaf(a.w, a.w, s);
  s = fmaf(b.x, b.x, s); s = fmaf(b.y, b.y, s); s = fmaf(b.z, b.z, s); s = fmaf(b.w, b.w, s);
  return s;
}

// ---------------- kernels ----------------

// the ONLY N^2 distance pass. Wave-uniform j vs 64 lane-i's x2; ballots staged
// in LDS; final phase: full-line stores + fused density popcount.
__global__ __launch_bounds__(ATHR) void k_adj(const float* __restrict__ X,
                                              unsigned int* __restrict__ adj,
                                              int* __restrict__ density) {
  __shared__ float4 xs[AJC][2];                 // 4 KB
  __shared__ float sqs[AJC];                    // 0.5 KB
  __shared__ unsigned long long stq[AJC * 8];   // 8 KB ballot stage
  int t = threadIdx.x;
  int lane = t & 63, wv = t >> 6;
  int j0 = blockIdx.y * AJC;
  if (t < AJC) {
    int j = j0 + t;
    float4 a = ((const float4*)X)[j * 2];
    float4 b = ((const float4*)X)[j * 2 + 1];
    xs[t][0] = a; xs[t][1] = b;
    sqs[t] = sq8(a, b);
  }
  int ib = blockIdx.x * AI;
  int i0 = ib + wv * 64 + lane, i1 = i0 + 256;
  v2f xi0[4], xi1[4];
  float sq0, sq1;
  {
    float4 a0 = ((const float4*)X)[i0 * 2], b0 = ((const float4*)X)[i0 * 2 + 1];
    float4 a1 = ((const float4*)X)[i1 * 2], b1 = ((const float4*)X)[i1 * 2 + 1];
    xi0[0] = (v2f){a0.x, a0.y}; xi0[1] = (v2f){a0.z, a0.w};
    xi0[2] = (v2f){b0.x, b0.y}; xi0[3] = (v2f){b0.z, b0.w};
    xi1[0] = (v2f){a1.x, a1.y}; xi1[1] = (v2f){a1.z, a1.w};
    xi1[2] = (v2f){b1.x, b1.y}; xi1[3] = (v2f){b1.z, b1.w};
    sq0 = sq8(a0, b0);          // identical chain as sqs -> adj exactly symmetric
    sq1 = sq8(a1, b1);
  }
  __syncthreads();
#pragma unroll 4
  for (int jj = 0; jj < AJC; jj++) {
    float4 xa = xs[jj][0], xb = xs[jj][1];
    float sj = sqs[jj];
    float d20 = (sq0 + sj) - 2.0f * dot8(xi0, xa, xb);
    float d21 = (sq1 + sj) - 2.0f * dot8(xi1, xa, xb);
    unsigned long long b0 = __ballot(d20 <= EPS2);
    unsigned long long b1 = __ballot(d21 <= EPS2);
    if (lane == 0) {
      stq[jj * 8 + wv] = b0;        // i's [ib+64wv .. +63]
      stq[jj * 8 + wv + 4] = b1;    // +256
    }
  }
  __syncthreads();
  // store phase: 4 rows per wave-iter; lane = r*16 + w; each store inst = 4
  // full 64B lines. Fused density: popc + 16-lane reduce + 1 atomic/row/block.
  const unsigned int* stw = (const unsigned int*)stq;
  int r4 = lane >> 4, w16 = lane & 15;
#pragma unroll
  for (int it = 0; it < AJC / 4 / 4; it++) {    // 8 iters: wave covers 32 rows
    int row = wv * (AJC / 4) + it * 4 + r4;
    unsigned int v = stw[row * 16 + w16];
    adj[(size_t)(j0 + row) * NW + (ib >> 5) + w16] = v;
    int pc = __popc(v);
    pc += __shfl_xor(pc, 1, 64);
    pc += __shfl_xor(pc, 2, 64);
    pc += __shfl_xor(pc, 4, 64);
    pc += __shfl_xor(pc, 8, 64);
    if (w16 == 0) atomicAdd(&density[j0 + row], pc);
  }
}

// corebm via ballot; block 0 zeroes the contracted bitmap  (R10 verbatim)
__global__ __launch_bounds__(256) void k_core(const int* __restrict__ density,
                                              unsigned long long* __restrict__ corebm,
                                              unsigned int* __restrict__ bm) {
  int t = threadIdx.x;
  if (blockIdx.x == 0) {
#pragma unroll
    for (int q = 0; q < RMAX * W / 256; q++) bm[t + q * 256] = 0u;
  }
  int i = blockIdx.x * 256 + t;
  unsigned long long m = __ballot(density[i] >= MINS);
  if ((t & 63) == 0) corebm[i >> 6] = m;
}

// hook[i] = min(i, first core neighbor j<i)  (R10 verbatim)
__global__ __launch_bounds__(256) void k_hookbm(const unsigned int* __restrict__ adj,
                                                const unsigned int* __restrict__ cb32,
                                                int* __restrict__ hook) {
  __shared__ unsigned int cb[NW];
  int t = threadIdx.x;
  for (int w = t; w < NW; w += 256) cb[w] = cb32[w];
  __syncthreads();
  int i = blockIdx.x * 256 + t;
  const unsigned int* row = adj + (size_t)i * NW;
  int wi = i >> 5;
  int m = i;
  for (int w = 0; w <= wi; w++) {
    unsigned int x = row[w] & cb[w];
    if (w == wi) x &= (1u << (i & 31)) - 1;
    if (x) { m = (w << 5) + __ffs(x) - 1; break; }
  }
  hook[i] = m;
}

// root ranks in LDS + hook-chase + labL  (R10 verbatim)
__global__ __launch_bounds__(1024) void k_rid(const int* __restrict__ density,
                                              const int* __restrict__ hook,
                                              int* __restrict__ Rptr,
                                              int* __restrict__ labL,
                                              int* __restrict__ bcount) {
  __shared__ unsigned short ridS[NPTS];
  __shared__ int wsum[16];
  int t = threadIdx.x;
  int lane = t & 63, wid = t >> 6;
  const int SEG = NPTS / 1024;  // 12
  int base = t * SEG;
  int flags = 0;
  int s = 0;
#pragma unroll
  for (int k = 0; k < SEG; k++) {
    int i = base + k;
    int f = (density[i] >= MINS && hook[i] == i) ? 1 : 0;
    flags |= f << k;
    s += f;
  }
  int segsum = s;
#pragma unroll
  for (int off = 1; off < 64; off <<= 1) {
    int n = __shfl_up(s, off, 64);
    if (lane >= off) s += n;
  }
  if (lane == 63) wsum[wid] = s;
  __syncthreads();
  int woff = 0;
  for (int w = 0; w < wid; w++) woff += wsum[w];
  int run = woff + s - segsum;
#pragma unroll
  for (int k = 0; k < SEG; k++) {
    ridS[base + k] = (unsigned short)run;
    run += (flags >> k) & 1;
  }
  if (t == 1023) *Rptr = run;
  if (t == 0) *bcount = 0;
  __syncthreads();
  for (int k = 0; k < SEG; k++) {
    int i = base + k;
    int lab = -1;
    if (density[i] >= MINS) {
      int v = i, h = hook[v];
      while (h != v) { v = h; h = hook[v]; }
      lab = min((int)ridS[v], RMAX - 1);
    }
    labL[i] = lab;
  }
}

// crossing-label edges -> contracted adjacency  (R10 verbatim)
__global__ __launch_bounds__(FB) void k_fillbm(const unsigned int* __restrict__ adj,
                                               const unsigned int* __restrict__ cb32,
                                               const int* __restrict__ labL,
                                               unsigned int* __restrict__ bm) {
  __shared__ unsigned int bmL[RMAX * W];
  __shared__ unsigned short labS[NPTS];
  __shared__ unsigned int cb[NW];
  int t = threadIdx.x;
  for (int q = t; q < RMAX * W; q += FB) bmL[q] = 0u;
  for (int q = t; q < NPTS; q += FB) labS[q] = (unsigned short)(labL[q] + 1);
  for (int w = t; w < NW; w += FB) cb[w] = cb32[w];
  __syncthreads();
  int lane = t & 63, wv = t >> 6;
  int gw = blockIdx.x * 4 + wv;
  for (int i = gw; i < NPTS; i += 4 * FBGRID) {
    int a0 = (int)labS[i] - 1;
    if (a0 < 0) continue;
    const unsigned int* row = adj + (size_t)i * NW;
    int wi = i >> 5;
    for (int w = wi + lane; w < NW; w += 64) {
      unsigned int x = row[w] & cb[w];
      if (w == wi) x &= (0xFFFFFFFEu << (i & 31));
      while (x) {
        int b = __ffs(x) - 1; x &= x - 1;
        int lj = (int)labS[(w << 5) + b] - 1;
        if (lj != a0) {
          atomicOr(&bmL[a0 * W + (lj >> 5)], 1u << (lj & 31));
          atomicOr(&bmL[lj * W + (a0 >> 5)], 1u << (a0 & 31));
        }
      }
    }
  }
  __syncthreads();
  for (int q = t; q < RMAX * W; q += FB) {
    unsigned int v = bmL[q];
    if (v) atomicOr(&bm[q], v);
  }
}

// CC of contracted graph + compact cluster ids  (R10 verbatim)
__global__ __launch_bounds__(RMAX) void k_cc(const unsigned int* __restrict__ bm,
                                             const int* __restrict__ Rptr,
                                             int* __restrict__ clab) {
  __shared__ int lbl[RMAX];
  __shared__ int mn[RMAX];
  __shared__ int chg, cmp;
  int a = threadIdx.x;
  int R = *Rptr; if (R > RMAX) R = RMAX;
  lbl[a] = a;
  __syncthreads();
  while (true) {
    int m = lbl[a];
    if (a < R) {
      const unsigned int* row = bm + a * W;
#pragma unroll
      for (int w = 0; w < W; w++) {
        unsigned int bits = row[w];
        while (bits) {
          int b = __ffs(bits) - 1;
          bits &= bits - 1;
          m = min(m, lbl[(w << 5) + b]);
        }
      }
    }
    mn[a] = m;
    if (a == 0) chg = 0;
    __syncthreads();
    int l = lbl[a];
    if (m < l) { atomicMin(&lbl[l], m); atomicMin(&lbl[a], m); chg = 1; }
    __syncthreads();
    while (true) {
      if (a == 0) cmp = 0;
      __syncthreads();
      int nl = lbl[lbl[a]];
      __syncthreads();
      if (nl < lbl[a]) { lbl[a] = nl; cmp = 1; }
      __syncthreads();
      if (!cmp) break;
    }
    if (!chg) break;
    __syncthreads();
  }
  int flag = (a < R && lbl[a] == a) ? 1 : 0;
  mn[a] = flag;
  __syncthreads();
  for (int off = 1; off < RMAX; off <<= 1) {
    int v = mn[a];
    int add = (a >= off) ? mn[a - off] : 0;
    __syncthreads();
    mn[a] = v + add;
    __syncthreads();
  }
  clab[a] = mn[lbl[a]] - 1;
}

// per-point labels + border list  (R10 verbatim)
__global__ __launch_bounds__(256) void k_labels(const int* __restrict__ labL,
                                                const int* __restrict__ clab,
                                                int* __restrict__ labArr,
                                                int* __restrict__ blist,
                                                int* __restrict__ bcount,
                                                float* __restrict__ out) {
  int i = blockIdx.x * blockDim.x + threadIdx.x;
  if (i >= NPTS) return;
  int a = labL[i];
  if (a >= 0) {
    int lab = clab[a];
    labArr[i] = lab;
    out[i] = (float)lab;
  } else {
    labArr[i] = BIGL;
    out[i] = -1.0f;
    int pos = atomicAdd(bcount, 1);
    blist[pos] = i;
  }
}

// border points  (R10 verbatim)
__global__ __launch_bounds__(FT) void k_border(const unsigned int* __restrict__ adj,
                                               const unsigned int* __restrict__ cb32,
                                               const int* __restrict__ labArr,
                                               const int* __restrict__ blist,
                                               const int* __restrict__ bcount,
                                               float* __restrict__ out) {
  __shared__ unsigned int cb[NW];
  __shared__ int wm[FT / 64];
  int t = threadIdx.x;
  for (int w = t; w < NW; w += FT) cb[w] = cb32[w];
  __syncthreads();
  int count = *bcount;
  for (int k = blockIdx.x; k < count; k += gridDim.x) {
    int p = blist[k];
    const unsigned int* row = adj + (size_t)p * NW;
    int m = BIGL;
    for (int w = t; w < NW; w += FT) {
      unsigned int x = row[w] & cb[w];
      while (x) {
        int b = __ffs(x) - 1; x &= x - 1;
        m = min(m, labArr[(w << 5) + b]);
      }
    }
#pragma unroll
    for (int off = 32; off >= 1; off >>= 1) m = min(m, __shfl_xor(m, off, 64));
    if ((t & 63) == 0) wm[t >> 6] = m;
    __syncthreads();
    if (t == 0) {
      int mm = min(wm[0], wm[1]);
      out[p] = (mm < BIGL) ? (float)mm : -1.0f;
    }
    __syncthreads();
  }
}

// ---------------- launch ----------------

extern "C" void kernel_launch(void* const* d_in, const int* in_sizes, int n_in,
                              void* d_out, int out_size, void* d_ws, size_t ws_size,
                              hipStream_t stream) {
  const float* X = (const float*)d_in[0];
  float* out = (float*)d_out;

  char* ws = (char*)d_ws;
  unsigned int* adj = (unsigned int*)ws;                     // 18,874,368 B
  size_t off = (size_t)NPTS * NW * 4;
  int* density = (int*)(ws + off);           off += 4 * NPTS;
  int* hook    = (int*)(ws + off);           off += 4 * NPTS;
  int* labL    = (int*)(ws + off);           off += 4 * NPTS;
  int* labArr  = (int*)(ws + off);           off += 4 * NPTS;
  int* blist   = (int*)(ws + off);           off += 4 * NPTS;
  unsigned long long* corebm = (unsigned long long*)(ws + off); off += 2048;
  unsigned int* bm = (unsigned int*)(ws + off); off += 4 * RMAX * W;
  int* clab    = (int*)(ws + off);           off += 4 * RMAX;
  int* Rptr    = (int*)(ws + off);
  int* bcount  = Rptr + 1;

  hipMemsetAsync(density, 0, 4 * NPTS, stream);

  dim3 gridA(ANIB, ANJB);   // 24 x 96 = 2304 blocks x 4 waves = 9 waves/SIMD

  k_adj<<<gridA, ATHR, 0, stream>>>(X, adj, density);
  k_core<<<NIB1, 256, 0, stream>>>(density, corebm, bm);
  k_hookbm<<<NIB1, 256, 0, stream>>>(adj, (const unsigned int*)corebm, hook);
  k_rid<<<1, 1024, 0, stream>>>(density, hook, Rptr, labL, bcount);
  k_fillbm<<<FBGRID, FB, 0, stream>>>(adj, (const unsigned int*)corebm, labL, bm);
  k_cc<<<1, RMAX, 0, stream>>>(bm, Rptr, clab);
  k_labels<<<NIB1, 256, 0, stream>>>(labL, clab, labArr, blist, bcount, out);
  k_border<<<256, FT, 0, stream>>>(adj, (const unsigned int*)corebm, labArr, blist, bcount, out);
}